// Round 8
// baseline (70.349 us; speedup 1.0000x reference)
//
#include <hip/hip_runtime.h>
#include <hip/hip_bf16.h>
#include <math.h>

// Problem constants: H=1024, E=48, R=32
#define Hh 1024
#define Ee 48
#define Rr 32
#define PITCH_A 1028            // emb LDS pitch (floats): 1028%32=4
#define PITCH_B 516             // phase-B row pitch: 516%32=4
#define SMEM_FLOATS (42*PITCH_B)   // 21672 floats = 86.7 KB (covers 16*PITCH_A too)

union F4 { float4 v; float f[4]; };

__device__ __forceinline__ unsigned sent(int b) { return 0x9E3779B9u * (unsigned)(b + 1); }

// ================= fused: phase A (T build) + flag barrier + phase B (triplets) ==========
// grid 256 x block 512, LDS 87KB -> 1 block/CU -> all co-resident.
__global__ __launch_bounds__(512) void fused(const float* __restrict__ ent,
                                             const float* __restrict__ rel,
                                             const float* __restrict__ W1,
                                             const float* __restrict__ b1,
                                             const float* __restrict__ W2,
                                             const float* __restrict__ b2,
                                             const int* __restrict__ starts,
                                             const int* __restrict__ maxd,
                                             float* __restrict__ T,
                                             unsigned* __restrict__ flags,
                                             float* __restrict__ out) {
    __shared__ float se[SMEM_FLOATS];
    const int tid = threadIdx.x;
    const int b = blockIdx.x;

    // ---------------- phase A: T[128][1024] = emb @ W1seg (+b1 on rel rows) ----------------
    {
        const int rt = b & 7;
        const int h0 = (b >> 3) * 32;
        const int row0 = rt * 16;

        const float* emb; int foff;
        if (row0 < 48)      { emb = ent + row0 * Hh;        foff = 0;      }
        else if (row0 < 80) { emb = rel + (row0 - 48) * Hh; foff = Hh;     }
        else                { emb = ent + (row0 - 80) * Hh; foff = 2 * Hh; }

        // stage 16 emb rows (64KB), f4-coalesced
        for (int q = 0; q < 8; ++q) {
            const int id4 = tid + q * 512;              // 16 rows x 256 f4
            const int r = id4 >> 8, o4 = id4 & 255;
            *reinterpret_cast<float4*>(&se[r * PITCH_A + o4 * 4]) =
                *reinterpret_cast<const float4*>(&emb[r * Hh + o4 * 4]);
        }
        __syncthreads();

        const int w    = tid >> 6;
        const int lane = tid & 63;
        const int h4g  = lane & 7;
        const int rsub = lane >> 3;
        const int r0 = rsub * 2, r1 = r0 + 1;
        const int fb = w * 128;

        const float* w1p = W1 + (size_t)(foff + fb) * Hh + h0 + h4g * 4;
        const float* e0p = se + r0 * PITCH_A + fb;
        const float* e1p = se + r1 * PITCH_A + fb;

        float acc0[4] = {0.f, 0.f, 0.f, 0.f};
        float acc1[4] = {0.f, 0.f, 0.f, 0.f};

        F4 wa[16], wb[16];

#define LOAD16(BUF, G)                                                        \
        _Pragma("unroll")                                                     \
        for (int c = 0; c < 16; ++c)                                          \
            BUF[c].v = *reinterpret_cast<const float4*>(w1p + (size_t)((G) * 16 + c) * Hh);

#define COMPUTE16(BUF, G)                                                     \
        _Pragma("unroll")                                                     \
        for (int s = 0; s < 4; ++s) {                                         \
            F4 e0, e1;                                                        \
            e0.v = *reinterpret_cast<const float4*>(e0p + (G) * 16 + s * 4);  \
            e1.v = *reinterpret_cast<const float4*>(e1p + (G) * 16 + s * 4);  \
            _Pragma("unroll")                                                 \
            for (int c4 = 0; c4 < 4; ++c4) {                                  \
                _Pragma("unroll")                                             \
                for (int hh = 0; hh < 4; ++hh) {                              \
                    acc0[hh] = fmaf(e0.f[c4], BUF[s * 4 + c4].f[hh], acc0[hh]); \
                    acc1[hh] = fmaf(e1.f[c4], BUF[s * 4 + c4].f[hh], acc1[hh]); \
                }                                                             \
            }                                                                 \
        }

        LOAD16(wa, 0);
        LOAD16(wb, 1); COMPUTE16(wa, 0);
        LOAD16(wa, 2); COMPUTE16(wb, 1);
        LOAD16(wb, 3); COMPUTE16(wa, 2);
        LOAD16(wa, 4); COMPUTE16(wb, 3);
        LOAD16(wb, 5); COMPUTE16(wa, 4);
        LOAD16(wa, 6); COMPUTE16(wb, 5);
        LOAD16(wb, 7); COMPUTE16(wa, 6);
        COMPUTE16(wb, 7);

#undef LOAD16
#undef COMPUTE16

        // reduce 8 wave-partials via LDS
        __syncthreads();
        {
            const int base = (w * 64 + lane) * 8;
            F4 o0, o1;
#pragma unroll
            for (int c = 0; c < 4; ++c) { o0.f[c] = acc0[c]; o1.f[c] = acc1[c]; }
            *reinterpret_cast<float4*>(&se[base])     = o0.v;
            *reinterpret_cast<float4*>(&se[base + 4]) = o1.v;
        }
        __syncthreads();
        {
            const int r = tid >> 5, h = tid & 31;
            const int src = ((r >> 1) * 8 + (h >> 2)) * 8 + (r & 1) * 4 + (h & 3);
            float s = 0.f;
#pragma unroll
            for (int ww = 0; ww < 8; ++ww) s += se[ww * 512 + src];
            const int row = row0 + r;
            if (row >= 48 && row < 80) s += b1[h0 + h];
            T[row * Hh + h0 + h] = s;
        }
    }

    // ---------------- publish: T tile globally visible, then set my flag ----------------
    __threadfence();
    __syncthreads();
    if (tid == 0)
        __hip_atomic_store(&flags[b], sent(b), __ATOMIC_RELEASE, __HIP_MEMORY_SCOPE_AGENT);

    if (b >= 192) return;      // 64 pure-producer blocks done

    // ---------------- barrier: wait for all 256 producer flags ----------------
    if (tid < 64) {
        const int s0 = tid * 4;
#pragma unroll
        for (int c = 0; c < 4; ++c) {
            const unsigned expv = sent(s0 + c);
            while (__hip_atomic_load(&flags[s0 + c], __ATOMIC_ACQUIRE,
                                     __HIP_MEMORY_SCOPE_AGENT) != expv)
                __builtin_amdgcn_s_sleep(1);
        }
    }
    __syncthreads();

    // ---------------- phase B: triplet logits, sigmoid+mask, write out ----------------
    {
        const int i  = b >> 2;
        const int js = (b >> 1) & 1;
        const int ks = b & 1;
        const int j0 = js * 24;
        const int k0 = ks * 16;

        const int w    = tid >> 6;
        const int lane = tid & 63;
        const int jG = lane & 7;
        const int kG = lane >> 3;

        float acc[3][2];
#pragma unroll
        for (int a = 0; a < 3; ++a) { acc[a][0] = 0.f; acc[a][1] = 0.f; }

        for (int c = 0; c < 2; ++c) {
            const int hbase = c * 512;
            __syncthreads();
            for (int q = 0; q < 11; ++q) {
                const int id4 = tid + q * 512;
                if (id4 < 5376) {
                    const int g = id4 >> 7, o4 = id4 & 127;
                    const float* src;
                    if (g == 41) src = W2 + hbase + o4 * 4;
                    else {
                        int grow;
                        if (g == 0)       grow = i;
                        else if (g < 17)  grow = 48 + k0 + (g - 1);
                        else              grow = 80 + j0 + (g - 17);
                        src = T + grow * Hh + hbase + o4 * 4;
                    }
                    *reinterpret_cast<float4*>(&se[g * PITCH_B + o4 * 4]) =
                        *reinterpret_cast<const float4*>(src);
                }
            }
            __syncthreads();

            const int hw = w * 64;
            const float* pa = se + hw;
            const float* pw = se + 41 * PITCH_B + hw;

#pragma unroll
            for (int s = 0; s < 16; ++s) {
                const int h4 = s * 4;
                F4 av, wv, rv[2], bv[3];
                av.v = *reinterpret_cast<const float4*>(pa + h4);
                wv.v = *reinterpret_cast<const float4*>(pw + h4);
#pragma unroll
                for (int tk = 0; tk < 2; ++tk)
                    rv[tk].v = *reinterpret_cast<const float4*>(se + (1 + kG + 8 * tk) * PITCH_B + hw + h4);
#pragma unroll
                for (int tj = 0; tj < 3; ++tj)
                    bv[tj].v = *reinterpret_cast<const float4*>(se + (17 + jG + 8 * tj) * PITCH_B + hw + h4);

#pragma unroll
                for (int cc = 0; cc < 4; ++cc) {
                    const float a = av.f[cc], w2v = wv.f[cc];
                    const float p0 = a + rv[0].f[cc];
                    const float p1 = a + rv[1].f[cc];
#pragma unroll
                    for (int tj = 0; tj < 3; ++tj) {
                        const float bb = bv[tj].f[cc];
                        float v0 = p0 + bb; v0 = v0 > 0.f ? v0 : 0.f;
                        acc[tj][0] = fmaf(v0, w2v, acc[tj][0]);
                        float v1 = p1 + bb; v1 = v1 > 0.f ? v1 : 0.f;
                        acc[tj][1] = fmaf(v1, w2v, acc[tj][1]);
                    }
                }
            }
        }

        __syncthreads();
#pragma unroll
        for (int tj = 0; tj < 3; ++tj)
#pragma unroll
            for (int tk = 0; tk < 2; ++tk)
                se[w * 384 + (tj * 8 + jG) * 16 + tk * 8 + kG] = acc[tj][tk];
        __syncthreads();
        if (tid < 384) {
            float s = b2[0];
#pragma unroll
            for (int ww = 0; ww < 8; ++ww) s += se[ww * 384 + tid];
            const int jl = tid >> 4, kl = tid & 15;
            const int j = j0 + jl, k = k0 + kl;
            const float sc = 1.f / (1.f + expf(-s));
            int di = starts[i] - starts[j]; if (di < 0) di = -di;
            const bool m = (i != j) && (di <= maxd[0]);
            out[(i * Ee + j) * Rr + k] = m ? sc : 0.f;
        }
    }
}

// ============================ fallback 2-kernel path (R7, proven) ============================
__global__ __launch_bounds__(512) void kA_table(const float* __restrict__ ent,
                                                const float* __restrict__ rel,
                                                const float* __restrict__ W1,
                                                const float* __restrict__ b1,
                                                float* __restrict__ T) {
    __shared__ float se[16 * PITCH_A];
    const int tid = threadIdx.x;
    const int rt = blockIdx.x & 7;
    const int h0 = (blockIdx.x >> 3) * 32;
    const int row0 = rt * 16;

    const float* emb; int foff;
    if (row0 < 48)      { emb = ent + row0 * Hh;        foff = 0;      }
    else if (row0 < 80) { emb = rel + (row0 - 48) * Hh; foff = Hh;     }
    else                { emb = ent + (row0 - 80) * Hh; foff = 2 * Hh; }

    for (int q = 0; q < 8; ++q) {
        const int id4 = tid + q * 512;
        const int r = id4 >> 8, o4 = id4 & 255;
        *reinterpret_cast<float4*>(&se[r * PITCH_A + o4 * 4]) =
            *reinterpret_cast<const float4*>(&emb[r * Hh + o4 * 4]);
    }
    __syncthreads();

    const int w    = tid >> 6;
    const int lane = tid & 63;
    const int h4g  = lane & 7;
    const int rsub = lane >> 3;
    const int r0 = rsub * 2, r1 = r0 + 1;
    const int fb = w * 128;

    const float* w1p = W1 + (size_t)(foff + fb) * Hh + h0 + h4g * 4;
    const float* e0p = se + r0 * PITCH_A + fb;
    const float* e1p = se + r1 * PITCH_A + fb;

    float acc0[4] = {0.f, 0.f, 0.f, 0.f};
    float acc1[4] = {0.f, 0.f, 0.f, 0.f};
    F4 wa[16], wb[16];

#define LOAD16(BUF, G)                                                        \
    _Pragma("unroll")                                                         \
    for (int c = 0; c < 16; ++c)                                              \
        BUF[c].v = *reinterpret_cast<const float4*>(w1p + (size_t)((G) * 16 + c) * Hh);
#define COMPUTE16(BUF, G)                                                     \
    _Pragma("unroll")                                                         \
    for (int s = 0; s < 4; ++s) {                                             \
        F4 e0, e1;                                                            \
        e0.v = *reinterpret_cast<const float4*>(e0p + (G) * 16 + s * 4);      \
        e1.v = *reinterpret_cast<const float4*>(e1p + (G) * 16 + s * 4);      \
        _Pragma("unroll")                                                     \
        for (int c4 = 0; c4 < 4; ++c4) {                                      \
            _Pragma("unroll")                                                 \
            for (int hh = 0; hh < 4; ++hh) {                                  \
                acc0[hh] = fmaf(e0.f[c4], BUF[s * 4 + c4].f[hh], acc0[hh]);   \
                acc1[hh] = fmaf(e1.f[c4], BUF[s * 4 + c4].f[hh], acc1[hh]);   \
            }                                                                 \
        }                                                                     \
    }

    LOAD16(wa, 0);
    LOAD16(wb, 1); COMPUTE16(wa, 0);
    LOAD16(wa, 2); COMPUTE16(wb, 1);
    LOAD16(wb, 3); COMPUTE16(wa, 2);
    LOAD16(wa, 4); COMPUTE16(wb, 3);
    LOAD16(wb, 5); COMPUTE16(wa, 4);
    LOAD16(wa, 6); COMPUTE16(wb, 5);
    LOAD16(wb, 7); COMPUTE16(wa, 6);
    COMPUTE16(wb, 7);
#undef LOAD16
#undef COMPUTE16

    __syncthreads();
    {
        const int base = (w * 64 + lane) * 8;
        F4 o0, o1;
#pragma unroll
        for (int c = 0; c < 4; ++c) { o0.f[c] = acc0[c]; o1.f[c] = acc1[c]; }
        *reinterpret_cast<float4*>(&se[base])     = o0.v;
        *reinterpret_cast<float4*>(&se[base + 4]) = o1.v;
    }
    __syncthreads();
    {
        const int r = tid >> 5, h = tid & 31;
        const int src = ((r >> 1) * 8 + (h >> 2)) * 8 + (r & 1) * 4 + (h & 3);
        float s = 0.f;
#pragma unroll
        for (int ww = 0; ww < 8; ++ww) s += se[ww * 512 + src];
        const int row = row0 + r;
        if (row >= 48 && row < 80) s += b1[h0 + h];
        T[row * Hh + h0 + h] = s;
    }
}

__global__ __launch_bounds__(512) void kB_triplets(const float* __restrict__ T,
                                                   const float* __restrict__ W2,
                                                   const float* __restrict__ b2,
                                                   const int* __restrict__ starts,
                                                   const int* __restrict__ maxd,
                                                   float* __restrict__ out) {
    __shared__ float se[42 * PITCH_B];
    const int tid = threadIdx.x;
    const int i  = blockIdx.x >> 2;
    const int js = (blockIdx.x >> 1) & 1;
    const int ks = blockIdx.x & 1;
    const int j0 = js * 24;
    const int k0 = ks * 16;

    const int w    = tid >> 6;
    const int lane = tid & 63;
    const int jG = lane & 7;
    const int kG = lane >> 3;

    float acc[3][2];
#pragma unroll
    for (int a = 0; a < 3; ++a) { acc[a][0] = 0.f; acc[a][1] = 0.f; }

    for (int c = 0; c < 2; ++c) {
        const int hbase = c * 512;
        __syncthreads();
        for (int q = 0; q < 11; ++q) {
            const int id4 = tid + q * 512;
            if (id4 < 5376) {
                const int g = id4 >> 7, o4 = id4 & 127;
                const float* src;
                if (g == 41) src = W2 + hbase + o4 * 4;
                else {
                    int grow;
                    if (g == 0)       grow = i;
                    else if (g < 17)  grow = 48 + k0 + (g - 1);
                    else              grow = 80 + j0 + (g - 17);
                    src = T + grow * Hh + hbase + o4 * 4;
                }
                *reinterpret_cast<float4*>(&se[g * PITCH_B + o4 * 4]) =
                    *reinterpret_cast<const float4*>(src);
            }
        }
        __syncthreads();

        const int hw = w * 64;
        const float* pa = se + hw;
        const float* pw = se + 41 * PITCH_B + hw;

#pragma unroll
        for (int s = 0; s < 16; ++s) {
            const int h4 = s * 4;
            F4 av, wv, rv[2], bv[3];
            av.v = *reinterpret_cast<const float4*>(pa + h4);
            wv.v = *reinterpret_cast<const float4*>(pw + h4);
#pragma unroll
            for (int tk = 0; tk < 2; ++tk)
                rv[tk].v = *reinterpret_cast<const float4*>(se + (1 + kG + 8 * tk) * PITCH_B + hw + h4);
#pragma unroll
            for (int tj = 0; tj < 3; ++tj)
                bv[tj].v = *reinterpret_cast<const float4*>(se + (17 + jG + 8 * tj) * PITCH_B + hw + h4);

#pragma unroll
            for (int cc = 0; cc < 4; ++cc) {
                const float a = av.f[cc], w2v = wv.f[cc];
                const float p0 = a + rv[0].f[cc];
                const float p1 = a + rv[1].f[cc];
#pragma unroll
                for (int tj = 0; tj < 3; ++tj) {
                    const float bb = bv[tj].f[cc];
                    float v0 = p0 + bb; v0 = v0 > 0.f ? v0 : 0.f;
                    acc[tj][0] = fmaf(v0, w2v, acc[tj][0]);
                    float v1 = p1 + bb; v1 = v1 > 0.f ? v1 : 0.f;
                    acc[tj][1] = fmaf(v1, w2v, acc[tj][1]);
                }
            }
        }
    }

    __syncthreads();
#pragma unroll
    for (int tj = 0; tj < 3; ++tj)
#pragma unroll
        for (int tk = 0; tk < 2; ++tk)
            se[w * 384 + (tj * 8 + jG) * 16 + tk * 8 + kG] = acc[tj][tk];
    __syncthreads();
    if (tid < 384) {
        float s = b2[0];
#pragma unroll
        for (int ww = 0; ww < 8; ++ww) s += se[ww * 384 + tid];
        const int jl = tid >> 4, kl = tid & 15;
        const int j = j0 + jl, k = k0 + kl;
        const float sc = 1.f / (1.f + expf(-s));
        int di = starts[i] - starts[j]; if (di < 0) di = -di;
        const bool m = (i != j) && (di <= maxd[0]);
        out[(i * Ee + j) * Rr + k] = m ? sc : 0.f;
    }
}

// ============================ launch ============================
extern "C" void kernel_launch(void* const* d_in, const int* in_sizes, int n_in,
                              void* d_out, int out_size, void* d_ws, size_t ws_size,
                              hipStream_t stream) {
    const float* ent    = (const float*)d_in[0];
    const float* rel    = (const float*)d_in[1];
    const float* W1     = (const float*)d_in[2];
    const float* b1     = (const float*)d_in[3];
    const float* W2     = (const float*)d_in[4];
    const float* b2     = (const float*)d_in[5];
    const int*   starts = (const int*)d_in[6];
    const int*   maxd   = (const int*)d_in[7];
    float* out = (float*)d_out;
    char* ws = (char*)d_ws;

    float* T = (float*)ws;                                  // 512 KB
    unsigned* flags = (unsigned*)(ws + ((size_t)1 << 20));  // 256 u32 at ws+1MB

    if (ws_size >= ((size_t)1 << 20) + 4096) {
        fused<<<256, 512, 0, stream>>>(ent, rel, W1, b1, W2, b2, starts, maxd,
                                       T, flags, out);
    } else {
        kA_table<<<256, 512, 0, stream>>>(ent, rel, W1, b1, T);
        kB_triplets<<<192, 512, 0, stream>>>(T, W2, b2, starts, maxd, out);
    }
}

// Round 9
// 28.525 us; speedup vs baseline: 2.4662x; 2.4662x over previous
//
#include <hip/hip_runtime.h>
#include <hip/hip_bf16.h>
#include <math.h>

// Problem constants: H=1024, E=48, R=32
#define Hh 1024
#define Ee 48
#define Rr 32
#define PITCH_A 1028     // emb LDS pitch (floats): 1028%32=4
#define GP_A 1028        // W1 h4-group pitch (floats): 256*4+4, %32=4
#define BKa 256          // kA f-chunk
#define PITCH_B 260      // kB row pitch (floats): 256+4, %32=4
#define CH_B 256         // kB h-chunk

union F4 { float4 v; float f[4]; };

// ================= kA: T[128][1024] = emb @ W1seg (+b1 on rel rows) =================
// grid 256 (rt=b&7: 16 rows; ht=b>>3: 32 h), block 512 (8 waves).
// W1 staged block-wide into LDS in 4 double-buffered 256-f chunks (fat coalesced
// loads, no register-pipeline dependence). wave w owns f-subrange w*32 per chunk;
// lane: h4g=lane&7 (4 h), rsub=lane>>3 (2 rows). Partials reduced across waves in LDS.
__global__ __launch_bounds__(512) void kA_table(const float* __restrict__ ent,
                                                const float* __restrict__ rel,
                                                const float* __restrict__ W1,
                                                const float* __restrict__ b1,
                                                float* __restrict__ T) {
    __shared__ float emb_s[16 * PITCH_A];   // 65.8 KB (also reused for reduce)
    __shared__ float w_s[2][8 * GP_A];      // 2 x 32.9 KB
    const int tid = threadIdx.x;
    const int rt = blockIdx.x & 7;
    const int h0 = (blockIdx.x >> 3) * 32;
    const int row0 = rt * 16;

    const float* emb; int foff;
    if (row0 < 48)      { emb = ent + row0 * Hh;        foff = 0;      }
    else if (row0 < 80) { emb = rel + (row0 - 48) * Hh; foff = Hh;     }
    else                { emb = ent + (row0 - 80) * Hh; foff = 2 * Hh; }

    // stage 16 emb rows (64KB), f4-coalesced
    for (int q = 0; q < 8; ++q) {
        const int id4 = tid + q * 512;              // 16 rows x 256 f4
        const int r = id4 >> 8, o4 = id4 & 255;
        *reinterpret_cast<float4*>(&emb_s[r * PITCH_A + o4 * 4]) =
            *reinterpret_cast<const float4*>(&emb[r * Hh + o4 * 4]);
    }

    const int w    = tid >> 6;
    const int lane = tid & 63;
    const int h4g  = lane & 7;
    const int rsub = lane >> 3;
    const int r0 = rsub * 2;

    // chunk staging: 256 f x 32 h = 32 KB; thread t: c4=t&7, frow=t>>3 (+64*q)
    const int sc4 = tid & 7;
    const int sfb = tid >> 3;
    auto stage = [&](int buf, int c) {
        const float* gp = &W1[(size_t)(foff + c * BKa + sfb) * Hh + h0 + sc4 * 4];
        float4 v0 = *reinterpret_cast<const float4*>(gp);
        float4 v1 = *reinterpret_cast<const float4*>(gp + (size_t)64 * Hh);
        float4 v2 = *reinterpret_cast<const float4*>(gp + (size_t)128 * Hh);
        float4 v3 = *reinterpret_cast<const float4*>(gp + (size_t)192 * Hh);
        float* lp = &w_s[buf][sc4 * GP_A + sfb * 4];
        *reinterpret_cast<float4*>(lp)       = v0;
        *reinterpret_cast<float4*>(lp + 256) = v1;
        *reinterpret_cast<float4*>(lp + 512) = v2;
        *reinterpret_cast<float4*>(lp + 768) = v3;
    };

    stage(0, 0);
    __syncthreads();

    float acc0[4] = {0.f, 0.f, 0.f, 0.f};
    float acc1[4] = {0.f, 0.f, 0.f, 0.f};

    for (int c = 0; c < 4; ++c) {
        if (c < 3) stage((c + 1) & 1, c + 1);

        const float* wp  = &w_s[c & 1][h4g * GP_A + (w * 32) * 4];
        const float* e0p = &emb_s[r0 * PITCH_A + c * BKa + w * 32];
        const float* e1p = e0p + PITCH_A;

#pragma unroll
        for (int s = 0; s < 8; ++s) {            // 8 x 4f = 32 f per chunk per wave
            F4 e0, e1;
            e0.v = *reinterpret_cast<const float4*>(e0p + s * 4);
            e1.v = *reinterpret_cast<const float4*>(e1p + s * 4);
#pragma unroll
            for (int ff = 0; ff < 4; ++ff) {
                F4 wv;
                wv.v = *reinterpret_cast<const float4*>(wp + (s * 4 + ff) * 4);
#pragma unroll
                for (int hh = 0; hh < 4; ++hh) {
                    acc0[hh] = fmaf(e0.f[ff], wv.f[hh], acc0[hh]);
                    acc1[hh] = fmaf(e1.f[ff], wv.f[hh], acc1[hh]);
                }
            }
        }
        __syncthreads();
    }

    // reduce 8 wave-partials via LDS (reuse emb_s region)
    {
        const int base = (w * 64 + lane) * 8;
        F4 o0, o1;
#pragma unroll
        for (int c = 0; c < 4; ++c) { o0.f[c] = acc0[c]; o1.f[c] = acc1[c]; }
        *reinterpret_cast<float4*>(&emb_s[base])     = o0.v;
        *reinterpret_cast<float4*>(&emb_s[base + 4]) = o1.v;
    }
    __syncthreads();
    {
        const int r = tid >> 5, h = tid & 31;
        const int src = ((r >> 1) * 8 + (h >> 2)) * 8 + (r & 1) * 4 + (h & 3);
        float s = 0.f;
#pragma unroll
        for (int ww = 0; ww < 8; ++ww) s += emb_s[ww * 512 + src];
        const int row = row0 + r;
        if (row >= 48 && row < 80) s += b1[h0 + h];
        T[row * Hh + h0 + h] = s;
    }
}

// ================= kB: triplet logits over full h, sigmoid+mask, write out =================
// grid 192 (i=b>>2, js=(b>>1)&1, ks=b&1), block 512 (8 waves).
// LDS rows [A(1)|R(16)|B(24)|W2] x 256-h chunk (pitch 260), 4 chunks double-buffered.
// wave w handles h-slice w*32 per chunk; lane: jG=lane&7 (3 j), kG=lane>>3 (2 k).
__global__ __launch_bounds__(512) void kB_triplets(const float* __restrict__ T,
                                                   const float* __restrict__ W2,
                                                   const float* __restrict__ b2,
                                                   const int* __restrict__ starts,
                                                   const int* __restrict__ maxd,
                                                   float* __restrict__ out) {
    __shared__ float se[2][42 * PITCH_B];   // 2 x 43.7 KB
    const int tid = threadIdx.x;
    const int i  = blockIdx.x >> 2;
    const int js = (blockIdx.x >> 1) & 1;
    const int ks = blockIdx.x & 1;
    const int j0 = js * 24;
    const int k0 = ks * 16;

    const int w    = tid >> 6;
    const int lane = tid & 63;
    const int jG = lane & 7;
    const int kG = lane >> 3;

    // chunk staging: 42 rows x 64 f4 = 2688 f4; q=0..4 full, q=5 guarded (tid<128)
    auto stage = [&](int buf, int c) {
        const int hbase = c * CH_B;
        float4 v0, v1, v2, v3, v4, v5;
        int a5 = -1;
#define SRC_OF(ID4, VV)                                                       \
        {                                                                     \
            const int g = (ID4) >> 6, o4 = (ID4) & 63;                        \
            const float* src;                                                 \
            if (g == 41) src = W2 + hbase + o4 * 4;                           \
            else {                                                            \
                int grow;                                                     \
                if (g == 0)       grow = i;                                   \
                else if (g < 17)  grow = 48 + k0 + (g - 1);                   \
                else              grow = 80 + j0 + (g - 17);                  \
                src = T + grow * Hh + hbase + o4 * 4;                         \
            }                                                                 \
            VV = *reinterpret_cast<const float4*>(src);                       \
        }
        SRC_OF(tid,          v0)
        SRC_OF(tid + 512,    v1)
        SRC_OF(tid + 1024,   v2)
        SRC_OF(tid + 1536,   v3)
        SRC_OF(tid + 2048,   v4)
        if (tid < 128) { SRC_OF(tid + 2560, v5) a5 = tid + 2560; }
#undef SRC_OF
        float* b = se[buf];
        {
            const int id4 = tid;        *reinterpret_cast<float4*>(&b[(id4 >> 6) * PITCH_B + (id4 & 63) * 4]) = v0;
        }
        { const int id4 = tid + 512;    *reinterpret_cast<float4*>(&b[(id4 >> 6) * PITCH_B + (id4 & 63) * 4]) = v1; }
        { const int id4 = tid + 1024;   *reinterpret_cast<float4*>(&b[(id4 >> 6) * PITCH_B + (id4 & 63) * 4]) = v2; }
        { const int id4 = tid + 1536;   *reinterpret_cast<float4*>(&b[(id4 >> 6) * PITCH_B + (id4 & 63) * 4]) = v3; }
        { const int id4 = tid + 2048;   *reinterpret_cast<float4*>(&b[(id4 >> 6) * PITCH_B + (id4 & 63) * 4]) = v4; }
        if (a5 >= 0) { *reinterpret_cast<float4*>(&b[(a5 >> 6) * PITCH_B + (a5 & 63) * 4]) = v5; }
    };

    stage(0, 0);
    __syncthreads();

    float acc[3][2];
#pragma unroll
    for (int a = 0; a < 3; ++a) { acc[a][0] = 0.f; acc[a][1] = 0.f; }

    for (int c = 0; c < 4; ++c) {
        if (c < 3) stage((c + 1) & 1, c + 1);

        const float* sm = se[c & 1];
        const int hw = w * 32;
        const float* pa = sm + hw;
        const float* pw = sm + 41 * PITCH_B + hw;

#pragma unroll
        for (int s = 0; s < 8; ++s) {
            const int h4 = s * 4;
            F4 av, wv, rv[2], bv[3];
            av.v = *reinterpret_cast<const float4*>(pa + h4);
            wv.v = *reinterpret_cast<const float4*>(pw + h4);
#pragma unroll
            for (int tk = 0; tk < 2; ++tk)
                rv[tk].v = *reinterpret_cast<const float4*>(sm + (1 + kG + 8 * tk) * PITCH_B + hw + h4);
#pragma unroll
            for (int tj = 0; tj < 3; ++tj)
                bv[tj].v = *reinterpret_cast<const float4*>(sm + (17 + jG + 8 * tj) * PITCH_B + hw + h4);

#pragma unroll
            for (int cc = 0; cc < 4; ++cc) {
                const float a = av.f[cc], w2v = wv.f[cc];
                const float p0 = a + rv[0].f[cc];
                const float p1 = a + rv[1].f[cc];
#pragma unroll
                for (int tj = 0; tj < 3; ++tj) {
                    const float bb = bv[tj].f[cc];
                    float v0 = p0 + bb; v0 = v0 > 0.f ? v0 : 0.f;
                    acc[tj][0] = fmaf(v0, w2v, acc[tj][0]);
                    float v1 = p1 + bb; v1 = v1 > 0.f ? v1 : 0.f;
                    acc[tj][1] = fmaf(v1, w2v, acc[tj][1]);
                }
            }
        }
        __syncthreads();
    }

    // cross-wave reduce (8 h-slices hold the same 384 triplets), then finalize
#pragma unroll
    for (int tj = 0; tj < 3; ++tj)
#pragma unroll
        for (int tk = 0; tk < 2; ++tk)
            se[0][w * 384 + (tj * 8 + jG) * 16 + tk * 8 + kG] = acc[tj][tk];
    __syncthreads();
    if (tid < 384) {
        float s = b2[0];
#pragma unroll
        for (int ww = 0; ww < 8; ++ww) s += se[0][ww * 384 + tid];
        const int jl = tid >> 4, kl = tid & 15;
        const int j = j0 + jl, k = k0 + kl;
        const float sc = 1.f / (1.f + expf(-s));
        int di = starts[i] - starts[j]; if (di < 0) di = -di;
        const bool m = (i != j) && (di <= maxd[0]);
        out[(i * Ee + j) * Rr + k] = m ? sc : 0.f;
    }
}

// ============================ launch ============================
extern "C" void kernel_launch(void* const* d_in, const int* in_sizes, int n_in,
                              void* d_out, int out_size, void* d_ws, size_t ws_size,
                              hipStream_t stream) {
    const float* ent    = (const float*)d_in[0];
    const float* rel    = (const float*)d_in[1];
    const float* W1     = (const float*)d_in[2];
    const float* b1     = (const float*)d_in[3];
    const float* W2     = (const float*)d_in[4];
    const float* b2     = (const float*)d_in[5];
    const int*   starts = (const int*)d_in[6];
    const int*   maxd   = (const int*)d_in[7];
    float* out = (float*)d_out;

    float* T = (float*)d_ws;                 // 128 x 1024 floats = 512 KB

    kA_table<<<256, 512, 0, stream>>>(ent, rel, W1, b1, T);
    kB_triplets<<<192, 512, 0, stream>>>(T, W2, b2, starts, maxd, out);
}